// Round 13
// baseline (180.425 us; speedup 1.0000x reference)
//
#include <hip/hip_runtime.h>

#define N 8192
#define DIN 64
#define DOUT 128
#define KNN 16
#define MSAMP 1024         /* presample columns, stride 8 (R11-verified) */
#define NBX 16             /* j-split in main scan (512 j per region) */
#define NST 8              /* stages per block: NST*64 = 512 j */
#define CAND_R 64          /* slots per (row, bx) region == wave width */
#define CAND_C (NBX * CAND_R)   /* 1024 per row */
#define EPS 1.0f           /* candidate-gate margin (passed r8-r11) */
#define DELTA_Q 64         /* verify-gate margin: 0.5 in dist units */
#define VCAP 128           /* verify-list capacity (expect ~45, >10 sigma) */

typedef unsigned long long u64;
typedef __attribute__((ext_vector_type(8))) short bf16x8;
typedef __attribute__((ext_vector_type(4))) float floatx4;

__device__ __forceinline__ unsigned mono(float f) {
    unsigned u = __float_as_uint(f);
    return (u & 0x80000000u) ? ~u : (u | 0x80000000u);
}
__device__ __forceinline__ unsigned short f2bf(float f) {   // RNE float->bf16
    unsigned u = __float_as_uint(f);
    return (unsigned short)((u + 0x7FFFu + ((u >> 16) & 1u)) >> 16);
}
__device__ __forceinline__ unsigned qdist(float dist) {     // round-up quant
    int q = (int)(dist * 128.0f) + 2;
    q = max(q, 0); return (unsigned)min(q, 65535);
}

// K1: fused pre (R8 geometry: 8 rows/block).  R13: W1 loop unrolled 8x --
// 16 independent L2 loads in flight instead of 2 (the loop was
// latency-exposed per iteration).  FMA order per accumulator unchanged
// (ascending kk) -> U,V bit-identical.
__global__ __launch_bounds__(256, 4) void k_pre(const float* __restrict__ x,
                                                const float* __restrict__ W1,
                                                const float* __restrict__ b1,
                                                float* __restrict__ sq,
                                                float* __restrict__ sqs,
                                                unsigned short* __restrict__ Xh,
                                                unsigned short* __restrict__ Xs,
                                                float* __restrict__ U,
                                                float* __restrict__ V) {
    __shared__ float xs[8][DIN];
    int t = threadIdx.x;
    int r0 = blockIdx.x * 8;
    if (t < 128) {
        float4 xv = ((const float4*)x)[(size_t)r0 * (DIN / 4) + t];
        ((float4*)xs)[t] = xv;
        ushort4 h4;
        h4.x = f2bf(xv.x); h4.y = f2bf(xv.y);
        h4.z = f2bf(xv.z); h4.w = f2bf(xv.w);
        *(ushort4*)&Xh[r0 * DIN + t * 4] = h4;
    }
    __syncthreads();
    if (t < 16) {                                    // sampled row r0 -> Xs
        const float* xr = xs[0];
        ushort4 h4;
        h4.x = f2bf(xr[t * 4 + 0]); h4.y = f2bf(xr[t * 4 + 1]);
        h4.z = f2bf(xr[t * 4 + 2]); h4.w = f2bf(xr[t * 4 + 3]);
        *(ushort4*)&Xs[(size_t)blockIdx.x * DIN + t * 4] = h4;
    }
    if (t < 8) {
        const float4* xr = (const float4*)xs[t];
        float s0 = 0.f, s1 = 0.f, s2 = 0.f, s3 = 0.f;
#pragma unroll
        for (int q = 0; q < DIN / 4; ++q) {
            float4 a = xr[q];
            s0 = fmaf(a.x, a.x, s0); s1 = fmaf(a.y, a.y, s1);
            s2 = fmaf(a.z, a.z, s2); s3 = fmaf(a.w, a.w, s3);
        }
        float sv = (s0 + s1) + (s2 + s3);
        sq[r0 + t] = sv;
        if (t == 0) sqs[blockIdx.x] = sv;            // sampled rows j = 8*scol
    }
    int o = t & 127, g = t >> 7;                     // g in {0,1}: rows g*4+u
    float aU[4], aV[4];
#pragma unroll
    for (int u = 0; u < 4; ++u) { aU[u] = 0.f; aV[u] = 0.f; }
    const float* Whi = W1 + o;
    const float* Wlo = W1 + DIN * DOUT + o;
#pragma unroll 8
    for (int kk = 0; kk < DIN; ++kk) {
        float whi = Whi[kk * DOUT];
        float wlo = Wlo[kk * DOUT];
        float wd = whi - wlo;
#pragma unroll
        for (int u = 0; u < 4; ++u) {
            float xvv = xs[g * 4 + u][kk];
            aU[u] = fmaf(xvv, wd, aU[u]);
            aV[u] = fmaf(xvv, wlo, aV[u]);
        }
    }
    float bb = b1[o];
#pragma unroll
    for (int u = 0; u < 4; ++u) {
        int r = r0 + g * 4 + u;
        U[(size_t)r * DOUT + o] = aU[u] + bb;
        V[(size_t)r * DOUT + o] = aV[u];
    }
}

// K2: fused presample + tau, SALU-free VALU radix (R9/R11-verified),
// MSAMP=1024, 14 rounds.  Unchanged from R12.
__global__ __launch_bounds__(1024, 4) void k_pretau(const unsigned short* __restrict__ Xh,
                                                    const unsigned short* __restrict__ Xs,
                                                    const float* __restrict__ sq,
                                                    const float* __restrict__ sqs,
                                                    float* __restrict__ tauf) {
    __shared__ __align__(16) unsigned short qls[16 * MSAMP];   // 32 KB
    int tid = threadIdx.x, w = tid >> 6, l = tid & 63;         // w in [0,16)
    int m = l & 15, quad = l >> 4, ko = quad * 8;
    int rt = blockIdx.x;
    int irow = rt * 16 + m;
    size_t arow = (size_t)irow * DIN;
    bf16x8 iH0 = *(const bf16x8*)(Xh + arow + ko);   // i-row frag (B)
    bf16x8 iH1 = *(const bf16x8*)(Xh + arow + 32 + ko);
    float si = sq[irow];
    int swz = (m & 7) << 4;
    for (int it = 0; it < 4; ++it) {                 // 16 waves x 4 tiles
        int s16 = w * 64 + it * 16;                  // scol tile base
        const unsigned short* sp = Xs + (size_t)(s16 + m) * DIN;  // dense rows
        bf16x8 sH0 = *(const bf16x8*)(sp + ko);      // sampled (A)
        bf16x8 sH1 = *(const bf16x8*)(sp + 32 + ko);
        floatx4 acc = {0.f, 0.f, 0.f, 0.f};
        acc = __builtin_amdgcn_mfma_f32_16x16x32_bf16(sH0, iH0, acc, 0, 0, 0);
        acc = __builtin_amdgcn_mfma_f32_16x16x32_bf16(sH1, iH1, acc, 0, 0, 0);
        int sc0 = s16 + quad * 4;                    // 4 consecutive scols
        float4 sj = *(const float4*)(sqs + sc0);
        unsigned q0 = qdist(fmaf(-2.0f, acc[0], si + sj.x));
        unsigned q1 = qdist(fmaf(-2.0f, acc[1], si + sj.y));
        unsigned q2 = qdist(fmaf(-2.0f, acc[2], si + sj.z));
        unsigned q3 = qdist(fmaf(-2.0f, acc[3], si + sj.w));
        u64 pk = (u64)q0 | ((u64)q1 << 16) | ((u64)q2 << 32) | ((u64)q3 << 48);
        *(u64*)&qls[m * MSAMP + (sc0 ^ swz)] = pk;   // multiset-preserving
    }
    __syncthreads();
    // wave w radix-selects row w; 16 values/lane, register-resident.
    const uint4* qv = (const uint4*)qls;             // 16B units
    unsigned v[16];
#pragma unroll
    for (int k = 0; k < 2; ++k) {
        uint4 t4 = qv[w * 128 + k * 64 + l];         // lane-contiguous 16B
        v[k*8+0] = t4.x & 0xFFFFu; v[k*8+1] = t4.x >> 16;
        v[k*8+2] = t4.y & 0xFFFFu; v[k*8+3] = t4.y >> 16;
        v[k*8+4] = t4.z & 0xFFFFu; v[k*8+5] = t4.z >> 16;
        v[k*8+6] = t4.w & 0xFFFFu; v[k*8+7] = t4.w >> 16;
    }
#pragma unroll
    for (int i = 0; i < 16; ++i)                     // pin in VGPRs
        asm volatile("" : "+v"(v[i]));
    unsigned p = 0;                                  // invariant: #{q < p} < 16
#pragma unroll
    for (int b = 13; b >= 0; --b) {                  // 14 rounds (R11-proven)
        unsigned c16 = p | (1u << b);
        int a0 = 0, a1 = 0, a2 = 0, a3 = 0;          // pure VALU, no SALU/vcc
#pragma unroll
        for (int i = 0; i < 4; ++i) {
            a0 += (int)(v[i]      - c16) >> 31;      // -1 iff v < c16
            a1 += (int)(v[4 + i]  - c16) >> 31;
            a2 += (int)(v[8 + i]  - c16) >> 31;
            a3 += (int)(v[12 + i] - c16) >> 31;
        }
        int neg = (a0 + a1) + (a2 + a3);             // -(local count)
#pragma unroll
        for (int mk = 1; mk < 64; mk <<= 1)          // butterfly (LDS pipe)
            neg += __shfl_xor(neg, mk);
        if (-neg < 16) p = c16;                      // wave-uniform
    }
    if (l == 0) tauf[rt * 16 + w] = (float)p * (1.0f / 128.0f);
}

// K3: MFMA main scan (NBX=16, 8 blocks/CU).  R13: LDS double-buffer with
// issue-early/write-late staging (T14): stage st+1 loads issue BEFORE
// compute of st (L2 latency hides under MFMA+gate), ds_write after, ONE
// barrier per stage (was 2).  Hazard proof: writes to buf B in iter k vs
// reads of B in iter k-1 are separated by barrier(k-1); vs reads in k+1 by
// barrier(k).  Same data, same math -> bit-identical.
__global__ __launch_bounds__(256, 8) void k_main(const unsigned short* __restrict__ Xh,
                                                 const float* __restrict__ sq,
                                                 const float* __restrict__ tauf,
                                                 unsigned* __restrict__ cand,
                                                 unsigned* __restrict__ cntpart) {
    __shared__ __align__(16) short ldsH[2][64 * 72];      // 18 KB
    int tid = threadIdx.x, w = tid >> 6, l = tid & 63;
    int m = l & 15, ko = (l >> 4) * 8;
    int bx = blockIdx.x;
    int rt = blockIdx.y * 4 + w;
    size_t arow = (size_t)(rt * 16 + m) * DIN;
    bf16x8 aH0 = *(const bf16x8*)(Xh + arow + ko);
    bf16x8 aH1 = *(const bf16x8*)(Xh + arow + 32 + ko);
    int rg[4]; float T[4]; float si[4]; int rowcnt[4];
#pragma unroll
    for (int reg = 0; reg < 4; ++reg) {
        rg[reg] = rt * 16 + (l >> 4) * 4 + reg;
        si[reg] = sq[rg[reg]];
        T[reg] = tauf[rg[reg]] + EPS - si[reg];
        rowcnt[reg] = 0;
    }
    int qs = l & 48;
    unsigned lmask = (1u << (l & 15)) - 1u;
    int srw = tid >> 3, scol8 = (tid & 7) * 8;

    int jb0 = bx * (NST * 64);
    // prologue: stage 0 -> buf 0
    *(bf16x8*)&ldsH[0][srw * 72 + scol8] =
        *(const bf16x8*)(Xh + (size_t)(jb0 + srw) * DIN + scol8);
    *(bf16x8*)&ldsH[0][(srw + 32) * 72 + scol8] =
        *(const bf16x8*)(Xh + (size_t)(jb0 + 32 + srw) * DIN + scol8);
    __syncthreads();

    for (int st = 0; st < NST; ++st) {
        int cur = st & 1;
        int jbase = jb0 + st * 64;
        bf16x8 n0, n1;
        if (st < NST - 1) {                               // issue next loads NOW
            int jn = jbase + 64;
            n0 = *(const bf16x8*)(Xh + (size_t)(jn + srw) * DIN + scol8);
            n1 = *(const bf16x8*)(Xh + (size_t)(jn + 32 + srw) * DIN + scol8);
        }
#pragma unroll
        for (int it = 0; it < 4; ++it) {
            int br = it * 16 + m;
            bf16x8 bH0 = *(const bf16x8*)&ldsH[cur][br * 72 + ko];
            bf16x8 bH1 = *(const bf16x8*)&ldsH[cur][br * 72 + 32 + ko];
            floatx4 acc = {0.f, 0.f, 0.f, 0.f};
            acc = __builtin_amdgcn_mfma_f32_16x16x32_bf16(aH0, bH0, acc, 0, 0, 0);
            acc = __builtin_amdgcn_mfma_f32_16x16x32_bf16(aH1, bH1, acc, 0, 0, 0);
            int jcol = jbase + it * 16 + m;
            float sqj = sq[jcol];
#pragma unroll
            for (int reg = 0; reg < 4; ++reg) {
                float tv = fmaf(-2.0f, acc[reg], sqj);   // dist - si
                bool pass = tv <= T[reg];
                u64 bal = __ballot(pass);
                if (bal) {                               // skip empty
                    unsigned m16 = (unsigned)((bal >> qs) & 0xFFFFull);
                    if (pass) {
                        int slot = rowcnt[reg] + __popc(m16 & lmask);
                        if (slot < CAND_R)
                            cand[(size_t)rg[reg] * CAND_C + bx * CAND_R + slot] =
                                (qdist(tv + si[reg]) << 16) | (unsigned)jcol;
                    }
                    rowcnt[reg] += __popc(m16);
                }
            }
        }
        if (st < NST - 1) {                               // write-late into buf^1
            *(bf16x8*)&ldsH[cur ^ 1][srw * 72 + scol8] = n0;
            *(bf16x8*)&ldsH[cur ^ 1][(srw + 32) * 72 + scol8] = n1;
        }
        __syncthreads();                                  // one barrier/stage
    }
    if ((l & 15) == 0) {
#pragma unroll
        for (int reg = 0; reg < 4; ++reg)
            cntpart[rg[reg] * NBX + bx] = (unsigned)min(rowcnt[reg], CAND_R);
    }
}

// K4: fused [exact | aggout] (R12-verified).  R13: rows with total
// candidate count <= VCAP SKIP the radix entirely -- the verify set is then
// all valid candidates (a superset in the same ballot-prefix order); exact
// rank-select returns the identical top-16 -> output bit-identical.  Branch
// is wave-uniform (cntpart loads are wave-uniform); all threads still reach
// the downstream __syncthreads.
__global__ __launch_bounds__(256, 8) void k_post(
    const float* __restrict__ x, const float* __restrict__ sq,
    const unsigned* __restrict__ cntpart, const unsigned* __restrict__ cand,
    const float* __restrict__ U, const float* __restrict__ V,
    const float* __restrict__ W2, const float* __restrict__ b2,
    float* __restrict__ out)
{
    __shared__ union {
        struct { unsigned short vlist[4][VCAP];           // 1 KB
                 u64 ekeys[4][VCAP]; } e;                 // 4 KB
        struct { float ag[4][DOUT];                       // 2 KB
                 float w2t[32 * DOUT]; } a;               // 16 KB
    } sm;
    __shared__ int knn_s[4][KNN];                         // survives both phases
    int t = threadIdx.x;
    int w = t >> 6, l = t & 63;
    int row = blockIdx.x * 4 + w;
    // ---------------- phase E: exact top-16 ----------------
    {
        unsigned c[NBX];
        int total = 0;
        const unsigned* cp = cntpart + (size_t)row * NBX; // wave-uniform -> s_load
#pragma unroll
        for (int b = 0; b < NBX; ++b) {
            c[b] = min(cp[b], (unsigned)CAND_R);
            total += (int)c[b];
        }
        const unsigned* crow = cand + (size_t)row * CAND_C;
        unsigned qq[NBX], kk[NBX];
#pragma unroll
        for (int u = 0; u < NBX; ++u) {                   // all loads independent
            unsigned kv = crow[u * 64 + l];               // coalesced 256B/reg
            kk[u] = kv;
            qq[u] = ((unsigned)l < c[u]) ? (kv >> 16) : 0xFFFFFFFFu;
        }
        unsigned thr;
        if (total > VCAP) {                               // wave-uniform branch
            unsigned p = 0;                               // radix-select q16
#pragma unroll
            for (int b = 13; b >= 0; --b) {               // 14 rounds (R12 proof)
                unsigned c16 = p | (1u << b);
                int cnt = 0;
#pragma unroll
                for (int u = 0; u < NBX; ++u)
                    cnt += __popcll(__ballot(qq[u] < c16));
                if (cnt < 16) p = c16;
            }
            thr = p + DELTA_Q;                            // verify gate on q
        } else {
            thr = 0xFFFFFFFEu;                            // all valid pass
        }
        int nv = 0;
        u64 lm = (l == 63) ? 0xFFFFFFFFFFFFFFFFull >> 1 : (1ull << l) - 1ull;
#pragma unroll
        for (int u = 0; u < NBX; ++u) {
            bool pred = qq[u] <= thr;                     // sentinel -> false
            u64 bal = __ballot(pred);
            int slot = nv + __popcll(bal & lm);
            if (pred && slot < VCAP)
                sm.e.vlist[w][slot] = (unsigned short)(kk[u] & 0xFFFFu);
            nv += __popcll(bal);
        }
        nv = min(nv, VCAP);
        __syncthreads();
        float sqi = sq[row];
        const float* xi = x + (size_t)row * DIN;          // wave-uniform
#pragma unroll
        for (int r = 0; r < VCAP / 64; ++r) {
            int v = l + 64 * r;
            if (v < nv) {
                int j = (int)sm.e.vlist[w][v];
                const float4* bj = (const float4*)(x + (size_t)j * DIN);
                float s0 = 0.f, s1 = 0.f, s2 = 0.f, s3 = 0.f;
                float4 rb[8];                             // 2x8 stages: same
#pragma unroll
                for (int q = 0; q < 8; ++q) rb[q] = bj[q];
#pragma unroll
                for (int q = 0; q < 8; ++q) {             // FMA order per acc
                    s0 = fmaf(xi[4 * q + 0], rb[q].x, s0);//  chain == r1-r11
                    s1 = fmaf(xi[4 * q + 1], rb[q].y, s1);
                    s2 = fmaf(xi[4 * q + 2], rb[q].z, s2);
                    s3 = fmaf(xi[4 * q + 3], rb[q].w, s3);
                }
#pragma unroll
                for (int q = 0; q < 8; ++q) rb[q] = bj[8 + q];
#pragma unroll
                for (int q = 0; q < 8; ++q) {
                    s0 = fmaf(xi[32 + 4 * q + 0], rb[q].x, s0);
                    s1 = fmaf(xi[32 + 4 * q + 1], rb[q].y, s1);
                    s2 = fmaf(xi[32 + 4 * q + 2], rb[q].z, s2);
                    s3 = fmaf(xi[32 + 4 * q + 3], rb[q].w, s3);
                }
                float d = (s0 + s1) + (s2 + s3);
                float dist = fmaf(-2.0f, d, sqi + sq[j]);
                sm.e.ekeys[w][v] = ((u64)mono(dist) << 32) | (unsigned)j;
            }
        }
#pragma unroll
        for (int r = 0; r < VCAP / 64; ++r) {             // all-pairs rank
            int v = l + 64 * r;
            if (v < nv) {
                u64 mykey = sm.e.ekeys[w][v];
                int rank = 0;
                for (int i = 0; i < nv; ++i)
                    rank += (sm.e.ekeys[w][i] < mykey) ? 1 : 0;
                if (rank < KNN)
                    knn_s[w][rank] = (int)(unsigned)(mykey & 0xFFFFFFFFull);
            }
        }
    }
    __syncthreads();                                      // e.* dead after this
    // ---------------- phase A: agg + W2 GEMM ----------------
    {
        int o = t & 127, g = t >> 7;                      // g in {0,1}: 2 rows
        int row0 = blockIdx.x * 4;
#pragma unroll
        for (int r = 0; r < 2; ++r) {
            int rr = g * 2 + r;
            int i = row0 + rr;
            float u = U[(size_t)i * DOUT + o];
            float acc = 0.f;
#pragma unroll
            for (int q = 0; q < KNN; ++q)                 // same q-order as ref
                acc += fmaxf(u + V[(size_t)knn_s[rr][q] * DOUT + o], 0.0f);
            sm.a.ag[rr][o] = acc * (1.0f / KNN);
        }
        float a2[2] = {0.f, 0.f};
#pragma unroll
        for (int tile = 0; tile < 4; ++tile) {
            __syncthreads();
#pragma unroll
            for (int u = 0; u < 4; ++u)                   // 16 KB coalesced stage
                ((float4*)sm.a.w2t)[t + u * 256] =
                    ((const float4*)(W2 + tile * 32 * DOUT))[t + u * 256];
            __syncthreads();
#pragma unroll
            for (int q4 = 0; q4 < 8; ++q4) {              // ag in f4 regs
                int kb = tile * 32 + q4 * 4;
                float4 a0 = *(const float4*)&sm.a.ag[g * 2 + 0][kb];
                float4 a1 = *(const float4*)&sm.a.ag[g * 2 + 1][kb];
                float w0 = sm.a.w2t[(q4 * 4 + 0) * DOUT + o];
                float w1 = sm.a.w2t[(q4 * 4 + 1) * DOUT + o];
                float w2v = sm.a.w2t[(q4 * 4 + 2) * DOUT + o];
                float w3 = sm.a.w2t[(q4 * 4 + 3) * DOUT + o];
                a2[0] = fmaf(a0.x, w0, a2[0]);  a2[1] = fmaf(a1.x, w0, a2[1]);
                a2[0] = fmaf(a0.y, w1, a2[0]);  a2[1] = fmaf(a1.y, w1, a2[1]);
                a2[0] = fmaf(a0.z, w2v, a2[0]); a2[1] = fmaf(a1.z, w2v, a2[1]);
                a2[0] = fmaf(a0.w, w3, a2[0]);  a2[1] = fmaf(a1.w, w3, a2[1]);
            }
        }
        float bb = b2[o];
#pragma unroll
        for (int r = 0; r < 2; ++r)
            out[(size_t)(row0 + g * 2 + r) * DOUT + o] = a2[r] + bb;
    }
}

extern "C" void kernel_launch(void* const* d_in, const int* in_sizes, int n_in,
                              void* d_out, int out_size, void* d_ws, size_t ws_size,
                              hipStream_t stream) {
    const float* x  = (const float*)d_in[0];
    const float* W1 = (const float*)d_in[1];
    const float* b1 = (const float*)d_in[2];
    const float* W2 = (const float*)d_in[3];
    const float* b2 = (const float*)d_in[4];
    float* out = (float*)d_out;

    char* ws = (char*)d_ws;
    float*          sq      = (float*)(ws);                      // 32 KB
    float*          sqs     = (float*)(ws + 32768);              // 4 KB
    float*          tauf    = (float*)(ws + 40960);              // 32 KB
    unsigned short* Xs      = (unsigned short*)(ws + 73728);     // 128 KB
    unsigned short* Xh      = (unsigned short*)(ws + 655360);    // 1 MB
    float*          U       = (float*)(ws + 2097152);            // 4 MB
    float*          V       = (float*)(ws + 6291456);            // 4 MB
    unsigned*       cntpart = (unsigned*)(ws + 10485760);        // 512 KB
    unsigned*       cand    = (unsigned*)(ws + 11534336);        // 32 MB
    // total ws use ~45 MB (<< 268 MB workspace)

    k_pre<<<N / 8, 256, 0, stream>>>(x, W1, b1, sq, sqs, Xh, Xs, U, V);
    k_pretau<<<N / 16, 1024, 0, stream>>>(Xh, Xs, sq, sqs, tauf);
    k_main<<<dim3(NBX, 128), 256, 0, stream>>>(Xh, sq, tauf, cand, cntpart);
    k_post<<<N / 4, 256, 0, stream>>>(x, sq, cntpart, cand, U, V, W2, b2, out);
}

// Round 14
// 159.091 us; speedup vs baseline: 1.1341x; 1.1341x over previous
//
#include <hip/hip_runtime.h>

#define N 8192
#define DIN 64
#define DOUT 128
#define KNN 16
#define MSAMP 1024         /* presample columns, stride 8 (R11-verified) */
#define NBX 16             /* j-split in main scan (512 j per region) */
#define NST 8              /* stages per block: NST*64 = 512 j */
#define CAND_R 64          /* slots per (row, bx) region == wave width */
#define CAND_C (NBX * CAND_R)   /* 1024 per row */
#define EPS 1.0f           /* candidate-gate margin (passed r8-r11) */
#define DELTA_Q 64         /* verify-gate margin: 0.5 in dist units */
#define VCAP 128           /* verify-list capacity (expect ~45, >10 sigma) */

typedef unsigned long long u64;
typedef __attribute__((ext_vector_type(8))) short bf16x8;
typedef __attribute__((ext_vector_type(4))) float floatx4;

__device__ __forceinline__ unsigned mono(float f) {
    unsigned u = __float_as_uint(f);
    return (u & 0x80000000u) ? ~u : (u | 0x80000000u);
}
__device__ __forceinline__ unsigned short f2bf(float f) {   // RNE float->bf16
    unsigned u = __float_as_uint(f);
    return (unsigned short)((u + 0x7FFFu + ((u >> 16) & 1u)) >> 16);
}
__device__ __forceinline__ unsigned qdist(float dist) {     // round-up quant
    int q = (int)(dist * 128.0f) + 2;
    q = max(q, 0); return (unsigned)min(q, 65535);
}

// K1: fused pre (R13-kept: 8 rows/block, W1 loop unrolled 8x for MLP).
__global__ __launch_bounds__(256, 4) void k_pre(const float* __restrict__ x,
                                                const float* __restrict__ W1,
                                                const float* __restrict__ b1,
                                                float* __restrict__ sq,
                                                float* __restrict__ sqs,
                                                unsigned short* __restrict__ Xh,
                                                unsigned short* __restrict__ Xs,
                                                float* __restrict__ U,
                                                float* __restrict__ V) {
    __shared__ float xs[8][DIN];
    int t = threadIdx.x;
    int r0 = blockIdx.x * 8;
    if (t < 128) {
        float4 xv = ((const float4*)x)[(size_t)r0 * (DIN / 4) + t];
        ((float4*)xs)[t] = xv;
        ushort4 h4;
        h4.x = f2bf(xv.x); h4.y = f2bf(xv.y);
        h4.z = f2bf(xv.z); h4.w = f2bf(xv.w);
        *(ushort4*)&Xh[r0 * DIN + t * 4] = h4;
    }
    __syncthreads();
    if (t < 16) {                                    // sampled row r0 -> Xs
        const float* xr = xs[0];
        ushort4 h4;
        h4.x = f2bf(xr[t * 4 + 0]); h4.y = f2bf(xr[t * 4 + 1]);
        h4.z = f2bf(xr[t * 4 + 2]); h4.w = f2bf(xr[t * 4 + 3]);
        *(ushort4*)&Xs[(size_t)blockIdx.x * DIN + t * 4] = h4;
    }
    if (t < 8) {
        const float4* xr = (const float4*)xs[t];
        float s0 = 0.f, s1 = 0.f, s2 = 0.f, s3 = 0.f;
#pragma unroll
        for (int q = 0; q < DIN / 4; ++q) {
            float4 a = xr[q];
            s0 = fmaf(a.x, a.x, s0); s1 = fmaf(a.y, a.y, s1);
            s2 = fmaf(a.z, a.z, s2); s3 = fmaf(a.w, a.w, s3);
        }
        float sv = (s0 + s1) + (s2 + s3);
        sq[r0 + t] = sv;
        if (t == 0) sqs[blockIdx.x] = sv;            // sampled rows j = 8*scol
    }
    int o = t & 127, g = t >> 7;                     // g in {0,1}: rows g*4+u
    float aU[4], aV[4];
#pragma unroll
    for (int u = 0; u < 4; ++u) { aU[u] = 0.f; aV[u] = 0.f; }
    const float* Whi = W1 + o;
    const float* Wlo = W1 + DIN * DOUT + o;
#pragma unroll 8
    for (int kk = 0; kk < DIN; ++kk) {
        float whi = Whi[kk * DOUT];
        float wlo = Wlo[kk * DOUT];
        float wd = whi - wlo;
#pragma unroll
        for (int u = 0; u < 4; ++u) {
            float xvv = xs[g * 4 + u][kk];
            aU[u] = fmaf(xvv, wd, aU[u]);
            aV[u] = fmaf(xvv, wlo, aV[u]);
        }
    }
    float bb = b1[o];
#pragma unroll
    for (int u = 0; u < 4; ++u) {
        int r = r0 + g * 4 + u;
        U[(size_t)r * DOUT + o] = aU[u] + bb;
        V[(size_t)r * DOUT + o] = aV[u];
    }
}

// K2: fused presample + tau, SALU-free VALU radix (R9/R11-verified),
// MSAMP=1024, 14 rounds.  Unchanged from R12.
__global__ __launch_bounds__(1024, 4) void k_pretau(const unsigned short* __restrict__ Xh,
                                                    const unsigned short* __restrict__ Xs,
                                                    const float* __restrict__ sq,
                                                    const float* __restrict__ sqs,
                                                    float* __restrict__ tauf) {
    __shared__ __align__(16) unsigned short qls[16 * MSAMP];   // 32 KB
    int tid = threadIdx.x, w = tid >> 6, l = tid & 63;         // w in [0,16)
    int m = l & 15, quad = l >> 4, ko = quad * 8;
    int rt = blockIdx.x;
    int irow = rt * 16 + m;
    size_t arow = (size_t)irow * DIN;
    bf16x8 iH0 = *(const bf16x8*)(Xh + arow + ko);   // i-row frag (B)
    bf16x8 iH1 = *(const bf16x8*)(Xh + arow + 32 + ko);
    float si = sq[irow];
    int swz = (m & 7) << 4;
    for (int it = 0; it < 4; ++it) {                 // 16 waves x 4 tiles
        int s16 = w * 64 + it * 16;                  // scol tile base
        const unsigned short* sp = Xs + (size_t)(s16 + m) * DIN;  // dense rows
        bf16x8 sH0 = *(const bf16x8*)(sp + ko);      // sampled (A)
        bf16x8 sH1 = *(const bf16x8*)(sp + 32 + ko);
        floatx4 acc = {0.f, 0.f, 0.f, 0.f};
        acc = __builtin_amdgcn_mfma_f32_16x16x32_bf16(sH0, iH0, acc, 0, 0, 0);
        acc = __builtin_amdgcn_mfma_f32_16x16x32_bf16(sH1, iH1, acc, 0, 0, 0);
        int sc0 = s16 + quad * 4;                    // 4 consecutive scols
        float4 sj = *(const float4*)(sqs + sc0);
        unsigned q0 = qdist(fmaf(-2.0f, acc[0], si + sj.x));
        unsigned q1 = qdist(fmaf(-2.0f, acc[1], si + sj.y));
        unsigned q2 = qdist(fmaf(-2.0f, acc[2], si + sj.z));
        unsigned q3 = qdist(fmaf(-2.0f, acc[3], si + sj.w));
        u64 pk = (u64)q0 | ((u64)q1 << 16) | ((u64)q2 << 32) | ((u64)q3 << 48);
        *(u64*)&qls[m * MSAMP + (sc0 ^ swz)] = pk;   // multiset-preserving
    }
    __syncthreads();
    // wave w radix-selects row w; 16 values/lane, register-resident.
    const uint4* qv = (const uint4*)qls;             // 16B units
    unsigned v[16];
#pragma unroll
    for (int k = 0; k < 2; ++k) {
        uint4 t4 = qv[w * 128 + k * 64 + l];         // lane-contiguous 16B
        v[k*8+0] = t4.x & 0xFFFFu; v[k*8+1] = t4.x >> 16;
        v[k*8+2] = t4.y & 0xFFFFu; v[k*8+3] = t4.y >> 16;
        v[k*8+4] = t4.z & 0xFFFFu; v[k*8+5] = t4.z >> 16;
        v[k*8+6] = t4.w & 0xFFFFu; v[k*8+7] = t4.w >> 16;
    }
#pragma unroll
    for (int i = 0; i < 16; ++i)                     // pin in VGPRs
        asm volatile("" : "+v"(v[i]));
    unsigned p = 0;                                  // invariant: #{q < p} < 16
#pragma unroll
    for (int b = 13; b >= 0; --b) {                  // 14 rounds (R11-proven)
        unsigned c16 = p | (1u << b);
        int a0 = 0, a1 = 0, a2 = 0, a3 = 0;          // pure VALU, no SALU/vcc
#pragma unroll
        for (int i = 0; i < 4; ++i) {
            a0 += (int)(v[i]      - c16) >> 31;      // -1 iff v < c16
            a1 += (int)(v[4 + i]  - c16) >> 31;
            a2 += (int)(v[8 + i]  - c16) >> 31;
            a3 += (int)(v[12 + i] - c16) >> 31;
        }
        int neg = (a0 + a1) + (a2 + a3);             // -(local count)
#pragma unroll
        for (int mk = 1; mk < 64; mk <<= 1)          // butterfly (LDS pipe)
            neg += __shfl_xor(neg, mk);
        if (-neg < 16) p = c16;                      // wave-uniform
    }
    if (l == 0) tauf[rt * 16 + w] = (float)p * (1.0f / 128.0f);
}

// K3: MFMA main scan (R13-kept: dbuf, issue-early/write-late, one
// barrier/stage.  Hazard proof: writes to buf B in iter k vs reads of B in
// iter k-1 separated by barrier(k-1); vs reads in k+1 by barrier(k)).
__global__ __launch_bounds__(256, 8) void k_main(const unsigned short* __restrict__ Xh,
                                                 const float* __restrict__ sq,
                                                 const float* __restrict__ tauf,
                                                 unsigned* __restrict__ cand,
                                                 unsigned* __restrict__ cntpart) {
    __shared__ __align__(16) short ldsH[2][64 * 72];      // 18 KB
    int tid = threadIdx.x, w = tid >> 6, l = tid & 63;
    int m = l & 15, ko = (l >> 4) * 8;
    int bx = blockIdx.x;
    int rt = blockIdx.y * 4 + w;
    size_t arow = (size_t)(rt * 16 + m) * DIN;
    bf16x8 aH0 = *(const bf16x8*)(Xh + arow + ko);
    bf16x8 aH1 = *(const bf16x8*)(Xh + arow + 32 + ko);
    int rg[4]; float T[4]; float si[4]; int rowcnt[4];
#pragma unroll
    for (int reg = 0; reg < 4; ++reg) {
        rg[reg] = rt * 16 + (l >> 4) * 4 + reg;
        si[reg] = sq[rg[reg]];
        T[reg] = tauf[rg[reg]] + EPS - si[reg];
        rowcnt[reg] = 0;
    }
    int qs = l & 48;
    unsigned lmask = (1u << (l & 15)) - 1u;
    int srw = tid >> 3, scol8 = (tid & 7) * 8;

    int jb0 = bx * (NST * 64);
    // prologue: stage 0 -> buf 0
    *(bf16x8*)&ldsH[0][srw * 72 + scol8] =
        *(const bf16x8*)(Xh + (size_t)(jb0 + srw) * DIN + scol8);
    *(bf16x8*)&ldsH[0][(srw + 32) * 72 + scol8] =
        *(const bf16x8*)(Xh + (size_t)(jb0 + 32 + srw) * DIN + scol8);
    __syncthreads();

    for (int st = 0; st < NST; ++st) {
        int cur = st & 1;
        int jbase = jb0 + st * 64;
        bf16x8 n0, n1;
        if (st < NST - 1) {                               // issue next loads NOW
            int jn = jbase + 64;
            n0 = *(const bf16x8*)(Xh + (size_t)(jn + srw) * DIN + scol8);
            n1 = *(const bf16x8*)(Xh + (size_t)(jn + 32 + srw) * DIN + scol8);
        }
#pragma unroll
        for (int it = 0; it < 4; ++it) {
            int br = it * 16 + m;
            bf16x8 bH0 = *(const bf16x8*)&ldsH[cur][br * 72 + ko];
            bf16x8 bH1 = *(const bf16x8*)&ldsH[cur][br * 72 + 32 + ko];
            floatx4 acc = {0.f, 0.f, 0.f, 0.f};
            acc = __builtin_amdgcn_mfma_f32_16x16x32_bf16(aH0, bH0, acc, 0, 0, 0);
            acc = __builtin_amdgcn_mfma_f32_16x16x32_bf16(aH1, bH1, acc, 0, 0, 0);
            int jcol = jbase + it * 16 + m;
            float sqj = sq[jcol];
#pragma unroll
            for (int reg = 0; reg < 4; ++reg) {
                float tv = fmaf(-2.0f, acc[reg], sqj);   // dist - si
                bool pass = tv <= T[reg];
                u64 bal = __ballot(pass);
                if (bal) {                               // skip empty
                    unsigned m16 = (unsigned)((bal >> qs) & 0xFFFFull);
                    if (pass) {
                        int slot = rowcnt[reg] + __popc(m16 & lmask);
                        if (slot < CAND_R)
                            cand[(size_t)rg[reg] * CAND_C + bx * CAND_R + slot] =
                                (qdist(tv + si[reg]) << 16) | (unsigned)jcol;
                    }
                    rowcnt[reg] += __popc(m16);
                }
            }
        }
        if (st < NST - 1) {                               // write-late into buf^1
            *(bf16x8*)&ldsH[cur ^ 1][srw * 72 + scol8] = n0;
            *(bf16x8*)&ldsH[cur ^ 1][(srw + 32) * 72 + scol8] = n1;
        }
        __syncthreads();                                  // one barrier/stage
    }
    if ((l & 15) == 0) {
#pragma unroll
        for (int reg = 0; reg < 4; ++reg)
            cntpart[rg[reg] * NBX + bx] = (unsigned)min(rowcnt[reg], CAND_R);
    }
}

// K4: fused [exact | aggout] -- EXACT R12 revert (fastest measured).  R13's
// radix-skip REGRESSED +24us: skipping the radix lets nv grow ~45 -> ~128,
// and phase E scales as nv (dots) + nv^2 (all-pairs rank).  The radix is
// the nv-COMPRESSOR, not overhead; never trade it for ballot savings.
__global__ __launch_bounds__(256, 8) void k_post(
    const float* __restrict__ x, const float* __restrict__ sq,
    const unsigned* __restrict__ cntpart, const unsigned* __restrict__ cand,
    const float* __restrict__ U, const float* __restrict__ V,
    const float* __restrict__ W2, const float* __restrict__ b2,
    float* __restrict__ out)
{
    __shared__ union {
        struct { unsigned short vlist[4][VCAP];           // 1 KB
                 u64 ekeys[4][VCAP]; } e;                 // 4 KB
        struct { float ag[4][DOUT];                       // 2 KB
                 float w2t[32 * DOUT]; } a;               // 16 KB
    } sm;
    __shared__ int knn_s[4][KNN];                         // survives both phases
    int t = threadIdx.x;
    int w = t >> 6, l = t & 63;
    int row = blockIdx.x * 4 + w;
    // ---------------- phase E: exact top-16 ----------------
    {
        unsigned c[NBX];
        const unsigned* cp = cntpart + (size_t)row * NBX; // wave-uniform -> s_load
#pragma unroll
        for (int b = 0; b < NBX; ++b) c[b] = min(cp[b], (unsigned)CAND_R);
        const unsigned* crow = cand + (size_t)row * CAND_C;
        unsigned qq[NBX], kk[NBX];
#pragma unroll
        for (int u = 0; u < NBX; ++u) {                   // all loads independent
            unsigned kv = crow[u * 64 + l];               // coalesced 256B/reg
            kk[u] = kv;
            qq[u] = ((unsigned)l < c[u]) ? (kv >> 16) : 0xFFFFFFFFu;
        }
        unsigned p = 0;                                   // radix-select q16
#pragma unroll
        for (int b = 13; b >= 0; --b) {                   // 14 rounds (R12 proof)
            unsigned c16 = p | (1u << b);
            int cnt = 0;
#pragma unroll
            for (int u = 0; u < NBX; ++u)
                cnt += __popcll(__ballot(qq[u] < c16));
            if (cnt < 16) p = c16;
        }
        unsigned thr = p + DELTA_Q;                       // verify gate on q
        int nv = 0;
        u64 lm = (l == 63) ? 0xFFFFFFFFFFFFFFFFull >> 1 : (1ull << l) - 1ull;
#pragma unroll
        for (int u = 0; u < NBX; ++u) {
            bool pred = qq[u] <= thr;                     // invalid qq -> false
            u64 bal = __ballot(pred);
            int slot = nv + __popcll(bal & lm);
            if (pred && slot < VCAP)
                sm.e.vlist[w][slot] = (unsigned short)(kk[u] & 0xFFFFu);
            nv += __popcll(bal);
        }
        nv = min(nv, VCAP);
        __syncthreads();
        float sqi = sq[row];
        const float* xi = x + (size_t)row * DIN;          // wave-uniform
#pragma unroll
        for (int r = 0; r < VCAP / 64; ++r) {
            int v = l + 64 * r;
            if (v < nv) {
                int j = (int)sm.e.vlist[w][v];
                const float4* bj = (const float4*)(x + (size_t)j * DIN);
                float s0 = 0.f, s1 = 0.f, s2 = 0.f, s3 = 0.f;
                float4 rb[8];                             // 2x8 stages: same
#pragma unroll
                for (int q = 0; q < 8; ++q) rb[q] = bj[q];
#pragma unroll
                for (int q = 0; q < 8; ++q) {             // FMA order per acc
                    s0 = fmaf(xi[4 * q + 0], rb[q].x, s0);//  chain == r1-r11
                    s1 = fmaf(xi[4 * q + 1], rb[q].y, s1);
                    s2 = fmaf(xi[4 * q + 2], rb[q].z, s2);
                    s3 = fmaf(xi[4 * q + 3], rb[q].w, s3);
                }
#pragma unroll
                for (int q = 0; q < 8; ++q) rb[q] = bj[8 + q];
#pragma unroll
                for (int q = 0; q < 8; ++q) {
                    s0 = fmaf(xi[32 + 4 * q + 0], rb[q].x, s0);
                    s1 = fmaf(xi[32 + 4 * q + 1], rb[q].y, s1);
                    s2 = fmaf(xi[32 + 4 * q + 2], rb[q].z, s2);
                    s3 = fmaf(xi[32 + 4 * q + 3], rb[q].w, s3);
                }
                float d = (s0 + s1) + (s2 + s3);
                float dist = fmaf(-2.0f, d, sqi + sq[j]);
                sm.e.ekeys[w][v] = ((u64)mono(dist) << 32) | (unsigned)j;
            }
        }
#pragma unroll
        for (int r = 0; r < VCAP / 64; ++r) {             // all-pairs rank
            int v = l + 64 * r;
            if (v < nv) {
                u64 mykey = sm.e.ekeys[w][v];
                int rank = 0;
                for (int i = 0; i < nv; ++i)
                    rank += (sm.e.ekeys[w][i] < mykey) ? 1 : 0;
                if (rank < KNN)
                    knn_s[w][rank] = (int)(unsigned)(mykey & 0xFFFFFFFFull);
            }
        }
    }
    __syncthreads();                                      // e.* dead after this
    // ---------------- phase A: agg + W2 GEMM ----------------
    {
        int o = t & 127, g = t >> 7;                      // g in {0,1}: 2 rows
        int row0 = blockIdx.x * 4;
#pragma unroll
        for (int r = 0; r < 2; ++r) {
            int rr = g * 2 + r;
            int i = row0 + rr;
            float u = U[(size_t)i * DOUT + o];
            float acc = 0.f;
#pragma unroll
            for (int q = 0; q < KNN; ++q)                 // same q-order as ref
                acc += fmaxf(u + V[(size_t)knn_s[rr][q] * DOUT + o], 0.0f);
            sm.a.ag[rr][o] = acc * (1.0f / KNN);
        }
        float a2[2] = {0.f, 0.f};
#pragma unroll
        for (int tile = 0; tile < 4; ++tile) {
            __syncthreads();
#pragma unroll
            for (int u = 0; u < 4; ++u)                   // 16 KB coalesced stage
                ((float4*)sm.a.w2t)[t + u * 256] =
                    ((const float4*)(W2 + tile * 32 * DOUT))[t + u * 256];
            __syncthreads();
#pragma unroll
            for (int q4 = 0; q4 < 8; ++q4) {              // ag in f4 regs
                int kb = tile * 32 + q4 * 4;
                float4 a0 = *(const float4*)&sm.a.ag[g * 2 + 0][kb];
                float4 a1 = *(const float4*)&sm.a.ag[g * 2 + 1][kb];
                float w0 = sm.a.w2t[(q4 * 4 + 0) * DOUT + o];
                float w1 = sm.a.w2t[(q4 * 4 + 1) * DOUT + o];
                float w2v = sm.a.w2t[(q4 * 4 + 2) * DOUT + o];
                float w3 = sm.a.w2t[(q4 * 4 + 3) * DOUT + o];
                a2[0] = fmaf(a0.x, w0, a2[0]);  a2[1] = fmaf(a1.x, w0, a2[1]);
                a2[0] = fmaf(a0.y, w1, a2[0]);  a2[1] = fmaf(a1.y, w1, a2[1]);
                a2[0] = fmaf(a0.z, w2v, a2[0]); a2[1] = fmaf(a1.z, w2v, a2[1]);
                a2[0] = fmaf(a0.w, w3, a2[0]);  a2[1] = fmaf(a1.w, w3, a2[1]);
            }
        }
        float bb = b2[o];
#pragma unroll
        for (int r = 0; r < 2; ++r)
            out[(size_t)(row0 + g * 2 + r) * DOUT + o] = a2[r] + bb;
    }
}

extern "C" void kernel_launch(void* const* d_in, const int* in_sizes, int n_in,
                              void* d_out, int out_size, void* d_ws, size_t ws_size,
                              hipStream_t stream) {
    const float* x  = (const float*)d_in[0];
    const float* W1 = (const float*)d_in[1];
    const float* b1 = (const float*)d_in[2];
    const float* W2 = (const float*)d_in[3];
    const float* b2 = (const float*)d_in[4];
    float* out = (float*)d_out;

    char* ws = (char*)d_ws;
    float*          sq      = (float*)(ws);                      // 32 KB
    float*          sqs     = (float*)(ws + 32768);              // 4 KB
    float*          tauf    = (float*)(ws + 40960);              // 32 KB
    unsigned short* Xs      = (unsigned short*)(ws + 73728);     // 128 KB
    unsigned short* Xh      = (unsigned short*)(ws + 655360);    // 1 MB
    float*          U       = (float*)(ws + 2097152);            // 4 MB
    float*          V       = (float*)(ws + 6291456);            // 4 MB
    unsigned*       cntpart = (unsigned*)(ws + 10485760);        // 512 KB
    unsigned*       cand    = (unsigned*)(ws + 11534336);        // 32 MB
    // total ws use ~45 MB (<< 268 MB workspace)

    k_pre<<<N / 8, 256, 0, stream>>>(x, W1, b1, sq, sqs, Xh, Xs, U, V);
    k_pretau<<<N / 16, 1024, 0, stream>>>(Xh, Xs, sq, sqs, tauf);
    k_main<<<dim3(NBX, 128), 256, 0, stream>>>(Xh, sq, tauf, cand, cntpart);
    k_post<<<N / 4, 256, 0, stream>>>(x, sq, cntpart, cand, U, V, W2, b2, out);
}

// Round 15
// 157.573 us; speedup vs baseline: 1.1450x; 1.0096x over previous
//
#include <hip/hip_runtime.h>

#define N 8192
#define DIN 64
#define DOUT 128
#define KNN 16
#define MSAMP 1024         /* presample columns, stride 8 (R11-verified) */
#define NBX 16             /* j-split in main scan (512 j per region) */
#define NST 8              /* stages per block: NST*64 = 512 j */
#define CAND_R 64          /* slots per (row, bx) region == wave width */
#define CAND_C (NBX * CAND_R)   /* 1024 per row */
#define EPS 1.0f           /* candidate-gate margin (passed r8-r11) */
#define DELTA_Q 64         /* verify-gate margin: 0.5 in dist units */
#define VCAP 128           /* verify-list capacity (expect ~45, >10 sigma) */

typedef unsigned long long u64;
typedef __attribute__((ext_vector_type(8))) short bf16x8;
typedef __attribute__((ext_vector_type(4))) float floatx4;

__device__ __forceinline__ unsigned mono(float f) {
    unsigned u = __float_as_uint(f);
    return (u & 0x80000000u) ? ~u : (u | 0x80000000u);
}
__device__ __forceinline__ unsigned short f2bf(float f) {   // RNE float->bf16
    unsigned u = __float_as_uint(f);
    return (unsigned short)((u + 0x7FFFu + ((u >> 16) & 1u)) >> 16);
}
__device__ __forceinline__ unsigned qdist(float dist) {     // round-up quant
    int q = (int)(dist * 128.0f) + 2;
    q = max(q, 0); return (unsigned)min(q, 65535);
}

// K1: fused pre.  R15: MLP inner loop reads xs as float4 (64 ds_read_b128
// per thread, was 256 scalar ds_read_b32).  The LDS pipe is per-CU shared:
// 16 waves x 256 x 5.8cy ~ 24k cy/CU was the kernel's dominant term (same
// signature as R12's k_post phase-A fix).  Per-accumulator FMA chain is
// kc-ascending, j-ascending == kk 0..63 ascending, W values unchanged ->
// U,V bit-identical.  All float4 lane indices compile-time (full unroll).
__global__ __launch_bounds__(256, 4) void k_pre(const float* __restrict__ x,
                                                const float* __restrict__ W1,
                                                const float* __restrict__ b1,
                                                float* __restrict__ sq,
                                                float* __restrict__ sqs,
                                                unsigned short* __restrict__ Xh,
                                                unsigned short* __restrict__ Xs,
                                                float* __restrict__ U,
                                                float* __restrict__ V) {
    __shared__ float xs[8][DIN];
    int t = threadIdx.x;
    int r0 = blockIdx.x * 8;
    if (t < 128) {
        float4 xv = ((const float4*)x)[(size_t)r0 * (DIN / 4) + t];
        ((float4*)xs)[t] = xv;
        ushort4 h4;
        h4.x = f2bf(xv.x); h4.y = f2bf(xv.y);
        h4.z = f2bf(xv.z); h4.w = f2bf(xv.w);
        *(ushort4*)&Xh[r0 * DIN + t * 4] = h4;
    }
    __syncthreads();
    if (t < 16) {                                    // sampled row r0 -> Xs
        const float* xr = xs[0];
        ushort4 h4;
        h4.x = f2bf(xr[t * 4 + 0]); h4.y = f2bf(xr[t * 4 + 1]);
        h4.z = f2bf(xr[t * 4 + 2]); h4.w = f2bf(xr[t * 4 + 3]);
        *(ushort4*)&Xs[(size_t)blockIdx.x * DIN + t * 4] = h4;
    }
    if (t < 8) {
        const float4* xr = (const float4*)xs[t];
        float s0 = 0.f, s1 = 0.f, s2 = 0.f, s3 = 0.f;
#pragma unroll
        for (int q = 0; q < DIN / 4; ++q) {
            float4 a = xr[q];
            s0 = fmaf(a.x, a.x, s0); s1 = fmaf(a.y, a.y, s1);
            s2 = fmaf(a.z, a.z, s2); s3 = fmaf(a.w, a.w, s3);
        }
        float sv = (s0 + s1) + (s2 + s3);
        sq[r0 + t] = sv;
        if (t == 0) sqs[blockIdx.x] = sv;            // sampled rows j = 8*scol
    }
    int o = t & 127, g = t >> 7;                     // g in {0,1}: rows g*4+u
    float aU[4], aV[4];
#pragma unroll
    for (int u = 0; u < 4; ++u) { aU[u] = 0.f; aV[u] = 0.f; }
    const float* Whi = W1 + o;
    const float* Wlo = W1 + DIN * DOUT + o;
#pragma unroll 4
    for (int kc = 0; kc < DIN / 4; ++kc) {
        float4 xv4[4];
#pragma unroll
        for (int u = 0; u < 4; ++u)                  // 4x ds_read_b128
            xv4[u] = *(const float4*)&xs[g * 4 + u][kc * 4];
        float wd[4], wl[4];
#pragma unroll
        for (int j = 0; j < 4; ++j) {
            float whi = Whi[(kc * 4 + j) * DOUT];
            wl[j] = Wlo[(kc * 4 + j) * DOUT];
            wd[j] = whi - wl[j];
        }
#pragma unroll
        for (int j = 0; j < 4; ++j) {                // kk = kc*4+j ascending
#pragma unroll
            for (int u = 0; u < 4; ++u) {
                float xvv = ((const float*)&xv4[u])[j];   // compile-time idx
                aU[u] = fmaf(xvv, wd[j], aU[u]);
                aV[u] = fmaf(xvv, wl[j], aV[u]);
            }
        }
    }
    float bb = b1[o];
#pragma unroll
    for (int u = 0; u < 4; ++u) {
        int r = r0 + g * 4 + u;
        U[(size_t)r * DOUT + o] = aU[u] + bb;
        V[(size_t)r * DOUT + o] = aV[u];
    }
}

// K2: fused presample + tau, SALU-free VALU radix (R9/R11-verified),
// MSAMP=1024, 14 rounds.  Unchanged from R12/R14.
__global__ __launch_bounds__(1024, 4) void k_pretau(const unsigned short* __restrict__ Xh,
                                                    const unsigned short* __restrict__ Xs,
                                                    const float* __restrict__ sq,
                                                    const float* __restrict__ sqs,
                                                    float* __restrict__ tauf) {
    __shared__ __align__(16) unsigned short qls[16 * MSAMP];   // 32 KB
    int tid = threadIdx.x, w = tid >> 6, l = tid & 63;         // w in [0,16)
    int m = l & 15, quad = l >> 4, ko = quad * 8;
    int rt = blockIdx.x;
    int irow = rt * 16 + m;
    size_t arow = (size_t)irow * DIN;
    bf16x8 iH0 = *(const bf16x8*)(Xh + arow + ko);   // i-row frag (B)
    bf16x8 iH1 = *(const bf16x8*)(Xh + arow + 32 + ko);
    float si = sq[irow];
    int swz = (m & 7) << 4;
    for (int it = 0; it < 4; ++it) {                 // 16 waves x 4 tiles
        int s16 = w * 64 + it * 16;                  // scol tile base
        const unsigned short* sp = Xs + (size_t)(s16 + m) * DIN;  // dense rows
        bf16x8 sH0 = *(const bf16x8*)(sp + ko);      // sampled (A)
        bf16x8 sH1 = *(const bf16x8*)(sp + 32 + ko);
        floatx4 acc = {0.f, 0.f, 0.f, 0.f};
        acc = __builtin_amdgcn_mfma_f32_16x16x32_bf16(sH0, iH0, acc, 0, 0, 0);
        acc = __builtin_amdgcn_mfma_f32_16x16x32_bf16(sH1, iH1, acc, 0, 0, 0);
        int sc0 = s16 + quad * 4;                    // 4 consecutive scols
        float4 sj = *(const float4*)(sqs + sc0);
        unsigned q0 = qdist(fmaf(-2.0f, acc[0], si + sj.x));
        unsigned q1 = qdist(fmaf(-2.0f, acc[1], si + sj.y));
        unsigned q2 = qdist(fmaf(-2.0f, acc[2], si + sj.z));
        unsigned q3 = qdist(fmaf(-2.0f, acc[3], si + sj.w));
        u64 pk = (u64)q0 | ((u64)q1 << 16) | ((u64)q2 << 32) | ((u64)q3 << 48);
        *(u64*)&qls[m * MSAMP + (sc0 ^ swz)] = pk;   // multiset-preserving
    }
    __syncthreads();
    // wave w radix-selects row w; 16 values/lane, register-resident.
    const uint4* qv = (const uint4*)qls;             // 16B units
    unsigned v[16];
#pragma unroll
    for (int k = 0; k < 2; ++k) {
        uint4 t4 = qv[w * 128 + k * 64 + l];         // lane-contiguous 16B
        v[k*8+0] = t4.x & 0xFFFFu; v[k*8+1] = t4.x >> 16;
        v[k*8+2] = t4.y & 0xFFFFu; v[k*8+3] = t4.y >> 16;
        v[k*8+4] = t4.z & 0xFFFFu; v[k*8+5] = t4.z >> 16;
        v[k*8+6] = t4.w & 0xFFFFu; v[k*8+7] = t4.w >> 16;
    }
#pragma unroll
    for (int i = 0; i < 16; ++i)                     // pin in VGPRs
        asm volatile("" : "+v"(v[i]));
    unsigned p = 0;                                  // invariant: #{q < p} < 16
#pragma unroll
    for (int b = 13; b >= 0; --b) {                  // 14 rounds (R11-proven)
        unsigned c16 = p | (1u << b);
        int a0 = 0, a1 = 0, a2 = 0, a3 = 0;          // pure VALU, no SALU/vcc
#pragma unroll
        for (int i = 0; i < 4; ++i) {
            a0 += (int)(v[i]      - c16) >> 31;      // -1 iff v < c16
            a1 += (int)(v[4 + i]  - c16) >> 31;
            a2 += (int)(v[8 + i]  - c16) >> 31;
            a3 += (int)(v[12 + i] - c16) >> 31;
        }
        int neg = (a0 + a1) + (a2 + a3);             // -(local count)
#pragma unroll
        for (int mk = 1; mk < 64; mk <<= 1)          // butterfly (LDS pipe)
            neg += __shfl_xor(neg, mk);
        if (-neg < 16) p = c16;                      // wave-uniform
    }
    if (l == 0) tauf[rt * 16 + w] = (float)p * (1.0f / 128.0f);
}

// K3: MFMA main scan (R13/R14-kept: dbuf, issue-early/write-late, one
// barrier/stage).
__global__ __launch_bounds__(256, 8) void k_main(const unsigned short* __restrict__ Xh,
                                                 const float* __restrict__ sq,
                                                 const float* __restrict__ tauf,
                                                 unsigned* __restrict__ cand,
                                                 unsigned* __restrict__ cntpart) {
    __shared__ __align__(16) short ldsH[2][64 * 72];      // 18 KB
    int tid = threadIdx.x, w = tid >> 6, l = tid & 63;
    int m = l & 15, ko = (l >> 4) * 8;
    int bx = blockIdx.x;
    int rt = blockIdx.y * 4 + w;
    size_t arow = (size_t)(rt * 16 + m) * DIN;
    bf16x8 aH0 = *(const bf16x8*)(Xh + arow + ko);
    bf16x8 aH1 = *(const bf16x8*)(Xh + arow + 32 + ko);
    int rg[4]; float T[4]; float si[4]; int rowcnt[4];
#pragma unroll
    for (int reg = 0; reg < 4; ++reg) {
        rg[reg] = rt * 16 + (l >> 4) * 4 + reg;
        si[reg] = sq[rg[reg]];
        T[reg] = tauf[rg[reg]] + EPS - si[reg];
        rowcnt[reg] = 0;
    }
    int qs = l & 48;
    unsigned lmask = (1u << (l & 15)) - 1u;
    int srw = tid >> 3, scol8 = (tid & 7) * 8;

    int jb0 = bx * (NST * 64);
    // prologue: stage 0 -> buf 0
    *(bf16x8*)&ldsH[0][srw * 72 + scol8] =
        *(const bf16x8*)(Xh + (size_t)(jb0 + srw) * DIN + scol8);
    *(bf16x8*)&ldsH[0][(srw + 32) * 72 + scol8] =
        *(const bf16x8*)(Xh + (size_t)(jb0 + 32 + srw) * DIN + scol8);
    __syncthreads();

    for (int st = 0; st < NST; ++st) {
        int cur = st & 1;
        int jbase = jb0 + st * 64;
        bf16x8 n0, n1;
        if (st < NST - 1) {                               // issue next loads NOW
            int jn = jbase + 64;
            n0 = *(const bf16x8*)(Xh + (size_t)(jn + srw) * DIN + scol8);
            n1 = *(const bf16x8*)(Xh + (size_t)(jn + 32 + srw) * DIN + scol8);
        }
#pragma unroll
        for (int it = 0; it < 4; ++it) {
            int br = it * 16 + m;
            bf16x8 bH0 = *(const bf16x8*)&ldsH[cur][br * 72 + ko];
            bf16x8 bH1 = *(const bf16x8*)&ldsH[cur][br * 72 + 32 + ko];
            floatx4 acc = {0.f, 0.f, 0.f, 0.f};
            acc = __builtin_amdgcn_mfma_f32_16x16x32_bf16(aH0, bH0, acc, 0, 0, 0);
            acc = __builtin_amdgcn_mfma_f32_16x16x32_bf16(aH1, bH1, acc, 0, 0, 0);
            int jcol = jbase + it * 16 + m;
            float sqj = sq[jcol];
#pragma unroll
            for (int reg = 0; reg < 4; ++reg) {
                float tv = fmaf(-2.0f, acc[reg], sqj);   // dist - si
                bool pass = tv <= T[reg];
                u64 bal = __ballot(pass);
                if (bal) {                               // skip empty
                    unsigned m16 = (unsigned)((bal >> qs) & 0xFFFFull);
                    if (pass) {
                        int slot = rowcnt[reg] + __popc(m16 & lmask);
                        if (slot < CAND_R)
                            cand[(size_t)rg[reg] * CAND_C + bx * CAND_R + slot] =
                                (qdist(tv + si[reg]) << 16) | (unsigned)jcol;
                    }
                    rowcnt[reg] += __popc(m16);
                }
            }
        }
        if (st < NST - 1) {                               // write-late into buf^1
            *(bf16x8*)&ldsH[cur ^ 1][srw * 72 + scol8] = n0;
            *(bf16x8*)&ldsH[cur ^ 1][(srw + 32) * 72 + scol8] = n1;
        }
        __syncthreads();                                  // one barrier/stage
    }
    if ((l & 15) == 0) {
#pragma unroll
        for (int reg = 0; reg < 4; ++reg)
            cntpart[rg[reg] * NBX + bx] = (unsigned)min(rowcnt[reg], CAND_R);
    }
}

// K4: fused [exact | aggout] -- R12 form (fastest measured).  Radix always
// runs: it is the nv-COMPRESSOR (R13 lesson: skipping it exploded nv and
// the O(nv^2) rank loop, +24us).
__global__ __launch_bounds__(256, 8) void k_post(
    const float* __restrict__ x, const float* __restrict__ sq,
    const unsigned* __restrict__ cntpart, const unsigned* __restrict__ cand,
    const float* __restrict__ U, const float* __restrict__ V,
    const float* __restrict__ W2, const float* __restrict__ b2,
    float* __restrict__ out)
{
    __shared__ union {
        struct { unsigned short vlist[4][VCAP];           // 1 KB
                 u64 ekeys[4][VCAP]; } e;                 // 4 KB
        struct { float ag[4][DOUT];                       // 2 KB
                 float w2t[32 * DOUT]; } a;               // 16 KB
    } sm;
    __shared__ int knn_s[4][KNN];                         // survives both phases
    int t = threadIdx.x;
    int w = t >> 6, l = t & 63;
    int row = blockIdx.x * 4 + w;
    // ---------------- phase E: exact top-16 ----------------
    {
        unsigned c[NBX];
        const unsigned* cp = cntpart + (size_t)row * NBX; // wave-uniform -> s_load
#pragma unroll
        for (int b = 0; b < NBX; ++b) c[b] = min(cp[b], (unsigned)CAND_R);
        const unsigned* crow = cand + (size_t)row * CAND_C;
        unsigned qq[NBX], kk[NBX];
#pragma unroll
        for (int u = 0; u < NBX; ++u) {                   // all loads independent
            unsigned kv = crow[u * 64 + l];               // coalesced 256B/reg
            kk[u] = kv;
            qq[u] = ((unsigned)l < c[u]) ? (kv >> 16) : 0xFFFFFFFFu;
        }
        unsigned p = 0;                                   // radix-select q16
#pragma unroll
        for (int b = 13; b >= 0; --b) {                   // 14 rounds (R12 proof)
            unsigned c16 = p | (1u << b);
            int cnt = 0;
#pragma unroll
            for (int u = 0; u < NBX; ++u)
                cnt += __popcll(__ballot(qq[u] < c16));
            if (cnt < 16) p = c16;
        }
        unsigned thr = p + DELTA_Q;                       // verify gate on q
        int nv = 0;
        u64 lm = (l == 63) ? 0xFFFFFFFFFFFFFFFFull >> 1 : (1ull << l) - 1ull;
#pragma unroll
        for (int u = 0; u < NBX; ++u) {
            bool pred = qq[u] <= thr;                     // invalid qq -> false
            u64 bal = __ballot(pred);
            int slot = nv + __popcll(bal & lm);
            if (pred && slot < VCAP)
                sm.e.vlist[w][slot] = (unsigned short)(kk[u] & 0xFFFFu);
            nv += __popcll(bal);
        }
        nv = min(nv, VCAP);
        __syncthreads();
        float sqi = sq[row];
        const float* xi = x + (size_t)row * DIN;          // wave-uniform
#pragma unroll
        for (int r = 0; r < VCAP / 64; ++r) {
            int v = l + 64 * r;
            if (v < nv) {
                int j = (int)sm.e.vlist[w][v];
                const float4* bj = (const float4*)(x + (size_t)j * DIN);
                float s0 = 0.f, s1 = 0.f, s2 = 0.f, s3 = 0.f;
                float4 rb[8];                             // 2x8 stages: same
#pragma unroll
                for (int q = 0; q < 8; ++q) rb[q] = bj[q];
#pragma unroll
                for (int q = 0; q < 8; ++q) {             // FMA order per acc
                    s0 = fmaf(xi[4 * q + 0], rb[q].x, s0);//  chain == r1-r11
                    s1 = fmaf(xi[4 * q + 1], rb[q].y, s1);
                    s2 = fmaf(xi[4 * q + 2], rb[q].z, s2);
                    s3 = fmaf(xi[4 * q + 3], rb[q].w, s3);
                }
#pragma unroll
                for (int q = 0; q < 8; ++q) rb[q] = bj[8 + q];
#pragma unroll
                for (int q = 0; q < 8; ++q) {
                    s0 = fmaf(xi[32 + 4 * q + 0], rb[q].x, s0);
                    s1 = fmaf(xi[32 + 4 * q + 1], rb[q].y, s1);
                    s2 = fmaf(xi[32 + 4 * q + 2], rb[q].z, s2);
                    s3 = fmaf(xi[32 + 4 * q + 3], rb[q].w, s3);
                }
                float d = (s0 + s1) + (s2 + s3);
                float dist = fmaf(-2.0f, d, sqi + sq[j]);
                sm.e.ekeys[w][v] = ((u64)mono(dist) << 32) | (unsigned)j;
            }
        }
#pragma unroll
        for (int r = 0; r < VCAP / 64; ++r) {             // all-pairs rank
            int v = l + 64 * r;
            if (v < nv) {
                u64 mykey = sm.e.ekeys[w][v];
                int rank = 0;
                for (int i = 0; i < nv; ++i)
                    rank += (sm.e.ekeys[w][i] < mykey) ? 1 : 0;
                if (rank < KNN)
                    knn_s[w][rank] = (int)(unsigned)(mykey & 0xFFFFFFFFull);
            }
        }
    }
    __syncthreads();                                      // e.* dead after this
    // ---------------- phase A: agg + W2 GEMM ----------------
    {
        int o = t & 127, g = t >> 7;                      // g in {0,1}: 2 rows
        int row0 = blockIdx.x * 4;
#pragma unroll
        for (int r = 0; r < 2; ++r) {
            int rr = g * 2 + r;
            int i = row0 + rr;
            float u = U[(size_t)i * DOUT + o];
            float acc = 0.f;
#pragma unroll
            for (int q = 0; q < KNN; ++q)                 // same q-order as ref
                acc += fmaxf(u + V[(size_t)knn_s[rr][q] * DOUT + o], 0.0f);
            sm.a.ag[rr][o] = acc * (1.0f / KNN);
        }
        float a2[2] = {0.f, 0.f};
#pragma unroll
        for (int tile = 0; tile < 4; ++tile) {
            __syncthreads();
#pragma unroll
            for (int u = 0; u < 4; ++u)                   // 16 KB coalesced stage
                ((float4*)sm.a.w2t)[t + u * 256] =
                    ((const float4*)(W2 + tile * 32 * DOUT))[t + u * 256];
            __syncthreads();
#pragma unroll
            for (int q4 = 0; q4 < 8; ++q4) {              // ag in f4 regs
                int kb = tile * 32 + q4 * 4;
                float4 a0 = *(const float4*)&sm.a.ag[g * 2 + 0][kb];
                float4 a1 = *(const float4*)&sm.a.ag[g * 2 + 1][kb];
                float w0 = sm.a.w2t[(q4 * 4 + 0) * DOUT + o];
                float w1 = sm.a.w2t[(q4 * 4 + 1) * DOUT + o];
                float w2v = sm.a.w2t[(q4 * 4 + 2) * DOUT + o];
                float w3 = sm.a.w2t[(q4 * 4 + 3) * DOUT + o];
                a2[0] = fmaf(a0.x, w0, a2[0]);  a2[1] = fmaf(a1.x, w0, a2[1]);
                a2[0] = fmaf(a0.y, w1, a2[0]);  a2[1] = fmaf(a1.y, w1, a2[1]);
                a2[0] = fmaf(a0.z, w2v, a2[0]); a2[1] = fmaf(a1.z, w2v, a2[1]);
                a2[0] = fmaf(a0.w, w3, a2[0]);  a2[1] = fmaf(a1.w, w3, a2[1]);
            }
        }
        float bb = b2[o];
#pragma unroll
        for (int r = 0; r < 2; ++r)
            out[(size_t)(row0 + g * 2 + r) * DOUT + o] = a2[r] + bb;
    }
}

extern "C" void kernel_launch(void* const* d_in, const int* in_sizes, int n_in,
                              void* d_out, int out_size, void* d_ws, size_t ws_size,
                              hipStream_t stream) {
    const float* x  = (const float*)d_in[0];
    const float* W1 = (const float*)d_in[1];
    const float* b1 = (const float*)d_in[2];
    const float* W2 = (const float*)d_in[3];
    const float* b2 = (const float*)d_in[4];
    float* out = (float*)d_out;

    char* ws = (char*)d_ws;
    float*          sq      = (float*)(ws);                      // 32 KB
    float*          sqs     = (float*)(ws + 32768);              // 4 KB
    float*          tauf    = (float*)(ws + 40960);              // 32 KB
    unsigned short* Xs      = (unsigned short*)(ws + 73728);     // 128 KB
    unsigned short* Xh      = (unsigned short*)(ws + 655360);    // 1 MB
    float*          U       = (float*)(ws + 2097152);            // 4 MB
    float*          V       = (float*)(ws + 6291456);            // 4 MB
    unsigned*       cntpart = (unsigned*)(ws + 10485760);        // 512 KB
    unsigned*       cand    = (unsigned*)(ws + 11534336);        // 32 MB
    // total ws use ~45 MB (<< 268 MB workspace)

    k_pre<<<N / 8, 256, 0, stream>>>(x, W1, b1, sq, sqs, Xh, Xs, U, V);
    k_pretau<<<N / 16, 1024, 0, stream>>>(Xh, Xs, sq, sqs, tauf);
    k_main<<<dim3(NBX, 128), 256, 0, stream>>>(Xh, sq, tauf, cand, cntpart);
    k_post<<<N / 4, 256, 0, stream>>>(x, sq, cntpart, cand, U, V, W2, b2, out);
}